// Round 1
// baseline (102.612 us; speedup 1.0000x reference)
//
#include <hip/hip_runtime.h>
#include <math.h>

#define BB 4
#define TT 1024
#define FF 256
#define UU 32
#define HALF_W 32      // ATT_WIDTH/2
#define WMAX 64

// ---------------------------------------------------------------------------
// Kernel A: per row (b,t) compute q'[row,u] = x[row]·Wt[:,u] + bh[u]
//                              k [row,u] = x[row]·Wx[:,u]
// 64 threads/block: lanes 0..31 -> q, 32..63 -> k. x row staged in LDS.
// ---------------------------------------------------------------------------
__global__ __launch_bounds__(64) void qk_kernel(
    const float* __restrict__ x, const float* __restrict__ Wt,
    const float* __restrict__ Wx, const float* __restrict__ bh,
    float* __restrict__ qbuf, float* __restrict__ kbuf) {
    int row = blockIdx.x;          // 0..B*T-1
    int tid = threadIdx.x;         // 0..63
    __shared__ float xs[FF];
    ((float4*)xs)[tid] = ((const float4*)(x + (size_t)row * FF))[tid];
    __syncthreads();
    int u = tid & 31;
    const float* W = (tid < 32) ? Wt : Wx;
    float acc = 0.f;
#pragma unroll 8
    for (int f = 0; f < FF; ++f)
        acc += xs[f] * W[f * UU + u];
    if (tid < 32) qbuf[row * UU + u] = acc + bh[u];
    else          kbuf[row * UU + u] = acc;
}

// ---------------------------------------------------------------------------
// Kernel B: one block (256 thr) per (b,t).
//   step 1: load q', Wa into LDS
//   step 2: 4 lanes per s-slot compute e_s = sum_u tanh(q'_u + k_su)*Wa_u + ba
//   step 3: 64-lane wave softmax over the window (exact; out-of-band == 0)
//   step 4: thread-per-f: v = sum_s a_s * x[b,s,f]  (coalesced x reads)
// ---------------------------------------------------------------------------
__global__ __launch_bounds__(256) void attn_kernel(
    const float* __restrict__ x, const float* __restrict__ qbuf,
    const float* __restrict__ kbuf, const float* __restrict__ Wa,
    const float* __restrict__ ba, float* __restrict__ out) {
    int row = blockIdx.x;          // b*T + t
    int t = row & (TT - 1);
    int b = row >> 10;
    int tid = threadIdx.x;
    int s0 = max(0, t - HALF_W);
    int s1 = min(TT, t + HALF_W);
    int W_ = s1 - s0;

    __shared__ float q_sh[UU];
    __shared__ float wa_sh[UU];
    __shared__ float e_sh[WMAX];
    __shared__ float a_sh[WMAX];

    if (tid < UU) {
        q_sh[tid]  = qbuf[row * UU + tid];
        wa_sh[tid] = Wa[tid];
    }
    __syncthreads();

    // step 2: logits. slot sl = tid/4 covers s = s0+sl; lane j = tid%4 sums 8 units.
    int sl = tid >> 2;
    int j  = tid & 3;
    float partial = 0.f;
    if (sl < W_) {
        const float* krow = kbuf + (size_t)(b * TT + s0 + sl) * UU + j * 8;
#pragma unroll
        for (int uu = 0; uu < 8; ++uu) {
            int u = j * 8 + uu;
            partial += tanhf(q_sh[u] + krow[uu]) * wa_sh[u];
        }
    }
    partial += __shfl_xor(partial, 1);
    partial += __shfl_xor(partial, 2);
    if (j == 0) e_sh[sl] = (sl < W_) ? partial + ba[0] : -1e30f;
    __syncthreads();

    // step 3: softmax across 64 slots in wave 0
    if (tid < 64) {
        float e = e_sh[tid];
        float m = e;
#pragma unroll
        for (int off = 1; off < 64; off <<= 1) m = fmaxf(m, __shfl_xor(m, off));
        float p = __expf(e - m);        // invalid slots: exp(-1e30-m) -> 0
        float sum = p;
#pragma unroll
        for (int off = 1; off < 64; off <<= 1) sum += __shfl_xor(sum, off);
        a_sh[tid] = p / sum;
    }
    __syncthreads();

    // step 4: weighted sum of x rows; thread == feature index (F == 256)
    float acc = 0.f;
    const float* xb = x + (size_t)(b * TT + s0) * FF + tid;
    for (int k2 = 0; k2 < W_; ++k2)
        acc += a_sh[k2] * xb[(size_t)k2 * FF];
    out[(size_t)row * FF + tid] = acc;
}

// ---------------------------------------------------------------------------
// Fallback (only if ws too small): fully fused, recomputes k per block.
// ---------------------------------------------------------------------------
__global__ __launch_bounds__(256) void fused_kernel(
    const float* __restrict__ x, const float* __restrict__ Wt,
    const float* __restrict__ Wx, const float* __restrict__ bh,
    const float* __restrict__ Wa, const float* __restrict__ ba,
    float* __restrict__ out) {
    int row = blockIdx.x;
    int t = row & (TT - 1);
    int b = row >> 10;
    int tid = threadIdx.x;
    int s0 = max(0, t - HALF_W);
    int s1 = min(TT, t + HALF_W);
    int W_ = s1 - s0;

    __shared__ float ks[WMAX * UU];   // 8 KB
    __shared__ float q_sh[UU];
    __shared__ float wa_sh[UU];
    __shared__ float e_sh[WMAX];
    __shared__ float a_sh[WMAX];

    if (tid < UU) {
        const float* xr = x + (size_t)row * FF;
        float acc = 0.f;
        for (int f = 0; f < FF; ++f) acc += xr[f] * Wt[f * UU + tid];
        q_sh[tid]  = acc + bh[tid];
        wa_sh[tid] = Wa[tid];
    }
    for (int p = tid; p < W_ * UU; p += 256) {
        int sl = p >> 5, u = p & 31;
        const float* xr = x + (size_t)(b * TT + s0 + sl) * FF;
        float acc = 0.f;
        for (int f = 0; f < FF; ++f) acc += xr[f] * Wx[f * UU + u];
        ks[p] = acc;
    }
    __syncthreads();

    int sl = tid >> 2;
    int j  = tid & 3;
    float partial = 0.f;
    if (sl < W_) {
#pragma unroll
        for (int uu = 0; uu < 8; ++uu) {
            int u = j * 8 + uu;
            partial += tanhf(q_sh[u] + ks[sl * UU + u]) * wa_sh[u];
        }
    }
    partial += __shfl_xor(partial, 1);
    partial += __shfl_xor(partial, 2);
    if (j == 0) e_sh[sl] = (sl < W_) ? partial + ba[0] : -1e30f;
    __syncthreads();

    if (tid < 64) {
        float e = e_sh[tid];
        float m = e;
#pragma unroll
        for (int off = 1; off < 64; off <<= 1) m = fmaxf(m, __shfl_xor(m, off));
        float p = __expf(e - m);
        float sum = p;
#pragma unroll
        for (int off = 1; off < 64; off <<= 1) sum += __shfl_xor(sum, off);
        a_sh[tid] = p / sum;
    }
    __syncthreads();

    float acc = 0.f;
    const float* xb = x + (size_t)(b * TT + s0) * FF + tid;
    for (int k2 = 0; k2 < W_; ++k2)
        acc += a_sh[k2] * xb[(size_t)k2 * FF];
    out[(size_t)row * FF + tid] = acc;
}

extern "C" void kernel_launch(void* const* d_in, const int* in_sizes, int n_in,
                              void* d_out, int out_size, void* d_ws, size_t ws_size,
                              hipStream_t stream) {
    const float* x  = (const float*)d_in[0];
    const float* Wt = (const float*)d_in[1];
    const float* Wx = (const float*)d_in[2];
    const float* bh = (const float*)d_in[3];
    const float* Wa = (const float*)d_in[4];
    const float* ba = (const float*)d_in[5];
    float* out = (float*)d_out;

    const size_t need = (size_t)2 * BB * TT * UU * sizeof(float);   // 1 MiB
    if (ws_size >= need) {
        float* qbuf = (float*)d_ws;
        float* kbuf = qbuf + (size_t)BB * TT * UU;
        qk_kernel<<<BB * TT, 64, 0, stream>>>(x, Wt, Wx, bh, qbuf, kbuf);
        attn_kernel<<<BB * TT, 256, 0, stream>>>(x, qbuf, kbuf, Wa, ba, out);
    } else {
        fused_kernel<<<BB * TT, 256, 0, stream>>>(x, Wt, Wx, bh, Wa, ba, out);
    }
}

// Round 2
// 91.963 us; speedup vs baseline: 1.1158x; 1.1158x over previous
//
#include <hip/hip_runtime.h>
#include <math.h>

#define BB 4
#define TT 1024
#define FF 256
#define UU 32
#define HALF_W 32      // ATT_WIDTH/2
#define WMAX 64

// fast tanh: 1 - 2/(exp(2x)+1); exact at +-inf ends, ~1e-6 rel err.
__device__ __forceinline__ float fast_tanh(float x) {
    float e = __expf(2.0f * x);
    return 1.0f - 2.0f / (e + 1.0f);
}

// ---------------------------------------------------------------------------
// Kernel A: 256 threads / block, 4 rows per block.
// thread t: r = t>>6 (row in block), half = (t>>5)&1 (0=q,1=k), u = t&31.
// x rows staged in LDS via float4; W lines reused 4x within block (L1).
// ---------------------------------------------------------------------------
__global__ __launch_bounds__(256) void qk_kernel(
    const float* __restrict__ x, const float* __restrict__ Wt,
    const float* __restrict__ Wx, const float* __restrict__ bh,
    float* __restrict__ qbuf, float* __restrict__ kbuf) {
    int row0 = blockIdx.x * 4;
    int tid = threadIdx.x;
    __shared__ float xs[4][FF];
    {
        // 4 rows x 256 floats = 256 float4; one per thread
        int r = tid >> 6;            // 0..3
        int c4 = tid & 63;           // float4 index within row
        ((float4*)xs[r])[c4] = ((const float4*)(x + (size_t)(row0 + r) * FF))[c4];
    }
    __syncthreads();
    int r = tid >> 6;
    int half = (tid >> 5) & 1;
    int u = tid & 31;
    const float* __restrict__ W = half ? Wx : Wt;
    const float* __restrict__ xr = xs[r];
    float acc = 0.f;
#pragma unroll 8
    for (int f = 0; f < FF; ++f)
        acc = fmaf(xr[f], W[f * UU + u], acc);
    int row = row0 + r;
    if (half == 0) qbuf[row * UU + u] = acc + bh[u];
    else           kbuf[row * UU + u] = acc;
}

// ---------------------------------------------------------------------------
// Kernel B: one block (256 thr) per (b,t).
// ---------------------------------------------------------------------------
__global__ __launch_bounds__(256) void attn_kernel(
    const float* __restrict__ x, const float* __restrict__ qbuf,
    const float* __restrict__ kbuf, const float* __restrict__ Wa,
    const float* __restrict__ ba, float* __restrict__ out) {
    int row = blockIdx.x;          // b*T + t
    int t = row & (TT - 1);
    int b = row >> 10;
    int tid = threadIdx.x;
    int s0 = max(0, t - HALF_W);
    int s1 = min(TT, t + HALF_W);
    int W_ = s1 - s0;

    __shared__ float q_sh[UU];
    __shared__ float wa_sh[UU];
    __shared__ float e_sh[WMAX];
    __shared__ float a_sh[WMAX];

    if (tid < UU) {
        q_sh[tid]  = qbuf[row * UU + tid];
        wa_sh[tid] = Wa[tid];
    }
    __syncthreads();

    // logits: slot sl = tid/4 covers s = s0+sl; lane j = tid%4 sums 8 units.
    int sl = tid >> 2;
    int j  = tid & 3;
    float partial = 0.f;
    if (sl < W_) {
        const float4* krow = (const float4*)(kbuf + (size_t)(b * TT + s0 + sl) * UU + j * 8);
        float4 k0 = krow[0];
        float4 k1 = krow[1];
        int u = j * 8;
        partial  = fast_tanh(q_sh[u + 0] + k0.x) * wa_sh[u + 0];
        partial += fast_tanh(q_sh[u + 1] + k0.y) * wa_sh[u + 1];
        partial += fast_tanh(q_sh[u + 2] + k0.z) * wa_sh[u + 2];
        partial += fast_tanh(q_sh[u + 3] + k0.w) * wa_sh[u + 3];
        partial += fast_tanh(q_sh[u + 4] + k1.x) * wa_sh[u + 4];
        partial += fast_tanh(q_sh[u + 5] + k1.y) * wa_sh[u + 5];
        partial += fast_tanh(q_sh[u + 6] + k1.z) * wa_sh[u + 6];
        partial += fast_tanh(q_sh[u + 7] + k1.w) * wa_sh[u + 7];
    }
    partial += __shfl_xor(partial, 1);
    partial += __shfl_xor(partial, 2);
    if (j == 0) e_sh[sl] = (sl < W_) ? partial + ba[0] : -1e30f;
    __syncthreads();

    // softmax across 64 slots in wave 0 (exact: out-of-band -> exp -> 0)
    if (tid < 64) {
        float e = e_sh[tid];
        float m = e;
#pragma unroll
        for (int off = 1; off < 64; off <<= 1) m = fmaxf(m, __shfl_xor(m, off));
        float p = __expf(e - m);
        float sum = p;
#pragma unroll
        for (int off = 1; off < 64; off <<= 1) sum += __shfl_xor(sum, off);
        a_sh[tid] = p / sum;
    }
    __syncthreads();

    // weighted sum of x rows; thread == feature index (F == 256)
    float acc = 0.f;
    const float* xb = x + (size_t)(b * TT + s0) * FF + tid;
#pragma unroll 4
    for (int k2 = 0; k2 < W_; ++k2)
        acc = fmaf(a_sh[k2], xb[(size_t)k2 * FF], acc);
    out[(size_t)row * FF + tid] = acc;
}

// ---------------------------------------------------------------------------
// Fallback (only if ws too small): fully fused, recomputes k per block.
// ---------------------------------------------------------------------------
__global__ __launch_bounds__(256) void fused_kernel(
    const float* __restrict__ x, const float* __restrict__ Wt,
    const float* __restrict__ Wx, const float* __restrict__ bh,
    const float* __restrict__ Wa, const float* __restrict__ ba,
    float* __restrict__ out) {
    int row = blockIdx.x;
    int t = row & (TT - 1);
    int b = row >> 10;
    int tid = threadIdx.x;
    int s0 = max(0, t - HALF_W);
    int s1 = min(TT, t + HALF_W);
    int W_ = s1 - s0;

    __shared__ float ks[WMAX * UU];   // 8 KB
    __shared__ float q_sh[UU];
    __shared__ float wa_sh[UU];
    __shared__ float e_sh[WMAX];
    __shared__ float a_sh[WMAX];

    if (tid < UU) {
        const float* xr = x + (size_t)row * FF;
        float acc = 0.f;
        for (int f = 0; f < FF; ++f) acc = fmaf(xr[f], Wt[f * UU + tid], acc);
        q_sh[tid]  = acc + bh[tid];
        wa_sh[tid] = Wa[tid];
    }
    for (int p = tid; p < W_ * UU; p += 256) {
        int sl = p >> 5, u = p & 31;
        const float* xr = x + (size_t)(b * TT + s0 + sl) * FF;
        float acc = 0.f;
        for (int f = 0; f < FF; ++f) acc = fmaf(xr[f], Wx[f * UU + u], acc);
        ks[p] = acc;
    }
    __syncthreads();

    int sl = tid >> 2;
    int j  = tid & 3;
    float partial = 0.f;
    if (sl < W_) {
#pragma unroll
        for (int uu = 0; uu < 8; ++uu) {
            int u = j * 8 + uu;
            partial += fast_tanh(q_sh[u] + ks[sl * UU + u]) * wa_sh[u];
        }
    }
    partial += __shfl_xor(partial, 1);
    partial += __shfl_xor(partial, 2);
    if (j == 0) e_sh[sl] = (sl < W_) ? partial + ba[0] : -1e30f;
    __syncthreads();

    if (tid < 64) {
        float e = e_sh[tid];
        float m = e;
#pragma unroll
        for (int off = 1; off < 64; off <<= 1) m = fmaxf(m, __shfl_xor(m, off));
        float p = __expf(e - m);
        float sum = p;
#pragma unroll
        for (int off = 1; off < 64; off <<= 1) sum += __shfl_xor(sum, off);
        a_sh[tid] = p / sum;
    }
    __syncthreads();

    float acc = 0.f;
    const float* xb = x + (size_t)(b * TT + s0) * FF + tid;
    for (int k2 = 0; k2 < W_; ++k2)
        acc = fmaf(a_sh[k2], xb[(size_t)k2 * FF], acc);
    out[(size_t)row * FF + tid] = acc;
}

extern "C" void kernel_launch(void* const* d_in, const int* in_sizes, int n_in,
                              void* d_out, int out_size, void* d_ws, size_t ws_size,
                              hipStream_t stream) {
    const float* x  = (const float*)d_in[0];
    const float* Wt = (const float*)d_in[1];
    const float* Wx = (const float*)d_in[2];
    const float* bh = (const float*)d_in[3];
    const float* Wa = (const float*)d_in[4];
    const float* ba = (const float*)d_in[5];
    float* out = (float*)d_out;

    const size_t need = (size_t)2 * BB * TT * UU * sizeof(float);   // 1 MiB
    if (ws_size >= need) {
        float* qbuf = (float*)d_ws;
        float* kbuf = qbuf + (size_t)BB * TT * UU;
        qk_kernel<<<BB * TT / 4, 256, 0, stream>>>(x, Wt, Wx, bh, qbuf, kbuf);
        attn_kernel<<<BB * TT, 256, 0, stream>>>(x, qbuf, kbuf, Wa, ba, out);
    } else {
        fused_kernel<<<BB * TT, 256, 0, stream>>>(x, Wt, Wx, bh, Wa, ba, out);
    }
}

// Round 3
// 90.371 us; speedup vs baseline: 1.1354x; 1.0176x over previous
//
#include <hip/hip_runtime.h>
#include <math.h>

#define BB 4
#define TT 1024
#define FF 256
#define UU 32
#define HALF_W 32      // ATT_WIDTH/2
#define WMAX 64
#define RB 8           // rows per qk block

// fast tanh: 1 - 2/(exp(2x)+1); ~1e-6 abs err, well under threshold.
__device__ __forceinline__ float fast_tanh(float x) {
    float e = __expf(2.0f * x);
    return 1.0f - 2.0f / (e + 1.0f);
}

// ---------------------------------------------------------------------------
// Kernel A: q'[row,u] = x[row]·Wt[:,u] + bh[u] ; k[row,u] = x[row]·Wx[:,u]
// 256 thr / block, RB=8 rows. 32 threads per row:
//   sub = tid&31: half = sub>>4 (0=q/Wt, 1=k/Wx), fh = (sub>>2)&3 (f quarter,
//   interleaved chunks), ug = (sub&3)*8 (8 consecutive u's in registers).
// Per thread: 16 iters x (1 LDS float4 of x + 8 float4 of W + 32 FMA)
//   -> 0.28 mem-ops/FMA instead of 2.0 in the previous version.
// f-chunks interleaved + row pad +4 keeps LDS aliasing <= 2-way (free).
// ---------------------------------------------------------------------------
__global__ __launch_bounds__(256) void qk_kernel(
    const float* __restrict__ x, const float* __restrict__ Wt,
    const float* __restrict__ Wx, const float* __restrict__ bh,
    float* __restrict__ qbuf, float* __restrict__ kbuf) {
    int row0 = blockIdx.x * RB;
    int tid = threadIdx.x;
    __shared__ float xs[RB][FF + 4];
    {
        // stage RB rows (RB*FF = 2048 floats = 512 float4), 2 per thread
        const float4* src = (const float4*)(x + (size_t)row0 * FF);
#pragma unroll
        for (int i = 0; i < 2; ++i) {
            int p = tid + i * 256;            // float4 index, 0..511
            int r = p >> 6;                   // row
            int c = p & 63;                   // float4 col
            *(float4*)&xs[r][c * 4] = src[p];
        }
    }
    __syncthreads();

    int r    = tid >> 5;          // 0..7
    int sub  = tid & 31;
    int half = sub >> 4;          // 0=q, 1=k
    int fh   = (sub >> 2) & 3;    // interleaved f-chunk id
    int ug   = (sub & 3) * 8;     // u offset
    const float* __restrict__ W = half ? Wx : Wt;
    const float* __restrict__ xr = xs[r];

    float acc[8] = {0.f, 0.f, 0.f, 0.f, 0.f, 0.f, 0.f, 0.f};
#pragma unroll 4
    for (int it = 0; it < 16; ++it) {
        int f = 4 * fh + 16 * it;             // float4 chunk base
        float4 x4 = *(const float4*)&xr[f];
#pragma unroll
        for (int j = 0; j < 4; ++j) {
            const float4* wp = (const float4*)(W + (size_t)(f + j) * UU + ug);
            float4 w0 = wp[0];
            float4 w1 = wp[1];
            float xv = (j == 0) ? x4.x : (j == 1) ? x4.y : (j == 2) ? x4.z : x4.w;
            acc[0] = fmaf(xv, w0.x, acc[0]);
            acc[1] = fmaf(xv, w0.y, acc[1]);
            acc[2] = fmaf(xv, w0.z, acc[2]);
            acc[3] = fmaf(xv, w0.w, acc[3]);
            acc[4] = fmaf(xv, w1.x, acc[4]);
            acc[5] = fmaf(xv, w1.y, acc[5]);
            acc[6] = fmaf(xv, w1.z, acc[6]);
            acc[7] = fmaf(xv, w1.w, acc[7]);
        }
    }
    // reduce across the 4 fh groups (lane-distance 4 and 8, same row/half/ug)
#pragma unroll
    for (int i = 0; i < 8; ++i) {
        acc[i] += __shfl_xor(acc[i], 4);
        acc[i] += __shfl_xor(acc[i], 8);
    }
    if (fh == 0) {
        int row = row0 + r;
        if (half == 0) {
            float4 b0 = *(const float4*)&bh[ug];
            float4 b1 = *(const float4*)&bh[ug + 4];
            float4 o0 = {acc[0] + b0.x, acc[1] + b0.y, acc[2] + b0.z, acc[3] + b0.w};
            float4 o1 = {acc[4] + b1.x, acc[5] + b1.y, acc[6] + b1.z, acc[7] + b1.w};
            *(float4*)&qbuf[(size_t)row * UU + ug]     = o0;
            *(float4*)&qbuf[(size_t)row * UU + ug + 4] = o1;
        } else {
            float4 o0 = {acc[0], acc[1], acc[2], acc[3]};
            float4 o1 = {acc[4], acc[5], acc[6], acc[7]};
            *(float4*)&kbuf[(size_t)row * UU + ug]     = o0;
            *(float4*)&kbuf[(size_t)row * UU + ug + 4] = o1;
        }
    }
}

// ---------------------------------------------------------------------------
// Kernel B: one block (256 thr) per (b,t).
// ---------------------------------------------------------------------------
__global__ __launch_bounds__(256) void attn_kernel(
    const float* __restrict__ x, const float* __restrict__ qbuf,
    const float* __restrict__ kbuf, const float* __restrict__ Wa,
    const float* __restrict__ ba, float* __restrict__ out) {
    int row = blockIdx.x;          // b*T + t
    int t = row & (TT - 1);
    int b = row >> 10;
    int tid = threadIdx.x;
    int s0 = max(0, t - HALF_W);
    int s1 = min(TT, t + HALF_W);
    int W_ = s1 - s0;

    __shared__ float q_sh[UU];
    __shared__ float wa_sh[UU];
    __shared__ float e_sh[WMAX];
    __shared__ float a_sh[WMAX];

    if (tid < UU) {
        q_sh[tid]  = qbuf[(size_t)row * UU + tid];
        wa_sh[tid] = Wa[tid];
    }
    __syncthreads();

    // logits: slot sl = tid/4 covers s = s0+sl; lane j = tid%4 sums 8 units.
    int sl = tid >> 2;
    int j  = tid & 3;
    float partial = 0.f;
    if (sl < W_) {
        const float4* krow = (const float4*)(kbuf + (size_t)(b * TT + s0 + sl) * UU + j * 8);
        float4 k0 = krow[0];
        float4 k1 = krow[1];
        int u = j * 8;
        partial  = fast_tanh(q_sh[u + 0] + k0.x) * wa_sh[u + 0];
        partial += fast_tanh(q_sh[u + 1] + k0.y) * wa_sh[u + 1];
        partial += fast_tanh(q_sh[u + 2] + k0.z) * wa_sh[u + 2];
        partial += fast_tanh(q_sh[u + 3] + k0.w) * wa_sh[u + 3];
        partial += fast_tanh(q_sh[u + 4] + k1.x) * wa_sh[u + 4];
        partial += fast_tanh(q_sh[u + 5] + k1.y) * wa_sh[u + 5];
        partial += fast_tanh(q_sh[u + 6] + k1.z) * wa_sh[u + 6];
        partial += fast_tanh(q_sh[u + 7] + k1.w) * wa_sh[u + 7];
    }
    partial += __shfl_xor(partial, 1);
    partial += __shfl_xor(partial, 2);
    if (j == 0) e_sh[sl] = (sl < W_) ? partial + ba[0] : -1e30f;
    __syncthreads();

    // softmax across 64 slots in wave 0 (exact: out-of-band -> exp -> 0)
    if (tid < 64) {
        float e = e_sh[tid];
        float m = e;
#pragma unroll
        for (int off = 1; off < 64; off <<= 1) m = fmaxf(m, __shfl_xor(m, off));
        float p = __expf(e - m);
        float sum = p;
#pragma unroll
        for (int off = 1; off < 64; off <<= 1) sum += __shfl_xor(sum, off);
        a_sh[tid] = p / sum;
    }
    __syncthreads();

    // weighted sum of x rows; thread == feature index (F == 256)
    float acc = 0.f;
    const float* xb = x + (size_t)(b * TT + s0) * FF + tid;
#pragma unroll 4
    for (int k2 = 0; k2 < W_; ++k2)
        acc = fmaf(a_sh[k2], xb[(size_t)k2 * FF], acc);
    out[(size_t)row * FF + tid] = acc;
}

// ---------------------------------------------------------------------------
// Fallback (only if ws too small): fully fused, recomputes k per block.
// ---------------------------------------------------------------------------
__global__ __launch_bounds__(256) void fused_kernel(
    const float* __restrict__ x, const float* __restrict__ Wt,
    const float* __restrict__ Wx, const float* __restrict__ bh,
    const float* __restrict__ Wa, const float* __restrict__ ba,
    float* __restrict__ out) {
    int row = blockIdx.x;
    int t = row & (TT - 1);
    int b = row >> 10;
    int tid = threadIdx.x;
    int s0 = max(0, t - HALF_W);
    int s1 = min(TT, t + HALF_W);
    int W_ = s1 - s0;

    __shared__ float ks[WMAX * UU];   // 8 KB
    __shared__ float q_sh[UU];
    __shared__ float wa_sh[UU];
    __shared__ float e_sh[WMAX];
    __shared__ float a_sh[WMAX];

    if (tid < UU) {
        const float* xr = x + (size_t)row * FF;
        float acc = 0.f;
        for (int f = 0; f < FF; ++f) acc = fmaf(xr[f], Wt[f * UU + tid], acc);
        q_sh[tid]  = acc + bh[tid];
        wa_sh[tid] = Wa[tid];
    }
    for (int p = tid; p < W_ * UU; p += 256) {
        int sl = p >> 5, u = p & 31;
        const float* xr = x + (size_t)(b * TT + s0 + sl) * FF;
        float acc = 0.f;
        for (int f = 0; f < FF; ++f) acc = fmaf(xr[f], Wx[f * UU + u], acc);
        ks[p] = acc;
    }
    __syncthreads();

    int sl = tid >> 2;
    int j  = tid & 3;
    float partial = 0.f;
    if (sl < W_) {
#pragma unroll
        for (int uu = 0; uu < 8; ++uu) {
            int u = j * 8 + uu;
            partial += fast_tanh(q_sh[u] + ks[sl * UU + u]) * wa_sh[u];
        }
    }
    partial += __shfl_xor(partial, 1);
    partial += __shfl_xor(partial, 2);
    if (j == 0) e_sh[sl] = (sl < W_) ? partial + ba[0] : -1e30f;
    __syncthreads();

    if (tid < 64) {
        float e = e_sh[tid];
        float m = e;
#pragma unroll
        for (int off = 1; off < 64; off <<= 1) m = fmaxf(m, __shfl_xor(m, off));
        float p = __expf(e - m);
        float sum = p;
#pragma unroll
        for (int off = 1; off < 64; off <<= 1) sum += __shfl_xor(sum, off);
        a_sh[tid] = p / sum;
    }
    __syncthreads();

    float acc = 0.f;
    const float* xb = x + (size_t)(b * TT + s0) * FF + tid;
    for (int k2 = 0; k2 < W_; ++k2)
        acc = fmaf(a_sh[k2], xb[(size_t)k2 * FF], acc);
    out[(size_t)row * FF + tid] = acc;
}

extern "C" void kernel_launch(void* const* d_in, const int* in_sizes, int n_in,
                              void* d_out, int out_size, void* d_ws, size_t ws_size,
                              hipStream_t stream) {
    const float* x  = (const float*)d_in[0];
    const float* Wt = (const float*)d_in[1];
    const float* Wx = (const float*)d_in[2];
    const float* bh = (const float*)d_in[3];
    const float* Wa = (const float*)d_in[4];
    const float* ba = (const float*)d_in[5];
    float* out = (float*)d_out;

    const size_t need = (size_t)2 * BB * TT * UU * sizeof(float);   // 1 MiB
    if (ws_size >= need) {
        float* qbuf = (float*)d_ws;
        float* kbuf = qbuf + (size_t)BB * TT * UU;
        qk_kernel<<<BB * TT / RB, 256, 0, stream>>>(x, Wt, Wx, bh, qbuf, kbuf);
        attn_kernel<<<BB * TT, 256, 0, stream>>>(x, qbuf, kbuf, Wa, ba, out);
    } else {
        fused_kernel<<<BB * TT, 256, 0, stream>>>(x, Wt, Wx, bh, Wa, ba, out);
    }
}

// Round 4
// 89.049 us; speedup vs baseline: 1.1523x; 1.0149x over previous
//
#include <hip/hip_runtime.h>
#include <math.h>

#define BB 4
#define TT 1024
#define FF 256
#define UU 32
#define HALF_W 32      // ATT_WIDTH/2
#define WMAX 64
#define RB 8           // rows per qk block

// fast tanh: 1 - 2/(exp(2x)+1); ~1e-6 abs err, well under threshold.
__device__ __forceinline__ float fast_tanh(float x) {
    float e = __expf(2.0f * x);
    return 1.0f - 2.0f / (e + 1.0f);
}

// ---------------------------------------------------------------------------
// Kernel A: q'[row,u] = x[row]·Wt[:,u] + bh[u] ; k[row,u] = x[row]·Wx[:,u]
// 256 thr / block, RB=8 rows, register-blocked (8 u's per thread, f split 4
// ways, shfl_xor reduction). ~0.28 mem-ops/FMA.
// ---------------------------------------------------------------------------
__global__ __launch_bounds__(256) void qk_kernel(
    const float* __restrict__ x, const float* __restrict__ Wt,
    const float* __restrict__ Wx, const float* __restrict__ bh,
    float* __restrict__ qbuf, float* __restrict__ kbuf) {
    int row0 = blockIdx.x * RB;
    int tid = threadIdx.x;
    __shared__ float xs[RB][FF + 4];
    {
        const float4* src = (const float4*)(x + (size_t)row0 * FF);
#pragma unroll
        for (int i = 0; i < 2; ++i) {
            int p = tid + i * 256;            // float4 index, 0..511
            int r = p >> 6;
            int c = p & 63;
            *(float4*)&xs[r][c * 4] = src[p];
        }
    }
    __syncthreads();

    int r    = tid >> 5;          // 0..7
    int sub  = tid & 31;
    int half = sub >> 4;          // 0=q, 1=k
    int fh   = (sub >> 2) & 3;    // interleaved f-chunk id
    int ug   = (sub & 3) * 8;     // u offset
    const float* __restrict__ W = half ? Wx : Wt;
    const float* __restrict__ xr = xs[r];

    float acc[8] = {0.f, 0.f, 0.f, 0.f, 0.f, 0.f, 0.f, 0.f};
#pragma unroll 4
    for (int it = 0; it < 16; ++it) {
        int f = 4 * fh + 16 * it;
        float4 x4 = *(const float4*)&xr[f];
#pragma unroll
        for (int j = 0; j < 4; ++j) {
            const float4* wp = (const float4*)(W + (size_t)(f + j) * UU + ug);
            float4 w0 = wp[0];
            float4 w1 = wp[1];
            float xv = (j == 0) ? x4.x : (j == 1) ? x4.y : (j == 2) ? x4.z : x4.w;
            acc[0] = fmaf(xv, w0.x, acc[0]);
            acc[1] = fmaf(xv, w0.y, acc[1]);
            acc[2] = fmaf(xv, w0.z, acc[2]);
            acc[3] = fmaf(xv, w0.w, acc[3]);
            acc[4] = fmaf(xv, w1.x, acc[4]);
            acc[5] = fmaf(xv, w1.y, acc[5]);
            acc[6] = fmaf(xv, w1.z, acc[6]);
            acc[7] = fmaf(xv, w1.w, acc[7]);
        }
    }
#pragma unroll
    for (int i = 0; i < 8; ++i) {
        acc[i] += __shfl_xor(acc[i], 4);
        acc[i] += __shfl_xor(acc[i], 8);
    }
    if (fh == 0) {
        int row = row0 + r;
        if (half == 0) {
            float4 b0 = *(const float4*)&bh[ug];
            float4 b1 = *(const float4*)&bh[ug + 4];
            float4 o0 = {acc[0] + b0.x, acc[1] + b0.y, acc[2] + b0.z, acc[3] + b0.w};
            float4 o1 = {acc[4] + b1.x, acc[5] + b1.y, acc[6] + b1.z, acc[7] + b1.w};
            *(float4*)&qbuf[(size_t)row * UU + ug]     = o0;
            *(float4*)&qbuf[(size_t)row * UU + ug + 4] = o1;
        } else {
            float4 o0 = {acc[0], acc[1], acc[2], acc[3]};
            float4 o1 = {acc[4], acc[5], acc[6], acc[7]};
            *(float4*)&kbuf[(size_t)row * UU + ug]     = o0;
            *(float4*)&kbuf[(size_t)row * UU + ug + 4] = o1;
        }
    }
}

// ---------------------------------------------------------------------------
// Kernel B: one block (256 thr) per (b,t).
// step 4 vectorized: lane covers 4 features (float4), window split 16 s/wave,
// cross-wave reduce via LDS. Invalid slots have a==0 exactly (exp(-1e30-m)),
// row index clamped so no OOB read.
// ---------------------------------------------------------------------------
__global__ __launch_bounds__(256) void attn_kernel(
    const float* __restrict__ x, const float* __restrict__ qbuf,
    const float* __restrict__ kbuf, const float* __restrict__ Wa,
    const float* __restrict__ ba, float* __restrict__ out) {
    int row = blockIdx.x;          // b*T + t
    int t = row & (TT - 1);
    int b = row >> 10;
    int tid = threadIdx.x;
    int s0 = max(0, t - HALF_W);
    int s1 = min(TT, t + HALF_W);
    int W_ = s1 - s0;

    __shared__ float q_sh[UU];
    __shared__ float wa_sh[UU];
    __shared__ float e_sh[WMAX];
    __shared__ float a_sh[WMAX];
    __shared__ float4 red[4][64];   // 4 KB cross-wave reduction buffer

    if (tid < UU) {
        q_sh[tid]  = qbuf[(size_t)row * UU + tid];
        wa_sh[tid] = Wa[tid];
    }
    __syncthreads();

    // logits: slot sl = tid/4 covers s = s0+sl; lane j = tid%4 sums 8 units.
    int sl = tid >> 2;
    int j  = tid & 3;
    float partial = 0.f;
    if (sl < W_) {
        const float4* krow = (const float4*)(kbuf + (size_t)(b * TT + s0 + sl) * UU + j * 8);
        float4 k0 = krow[0];
        float4 k1 = krow[1];
        int u = j * 8;
        partial  = fast_tanh(q_sh[u + 0] + k0.x) * wa_sh[u + 0];
        partial += fast_tanh(q_sh[u + 1] + k0.y) * wa_sh[u + 1];
        partial += fast_tanh(q_sh[u + 2] + k0.z) * wa_sh[u + 2];
        partial += fast_tanh(q_sh[u + 3] + k0.w) * wa_sh[u + 3];
        partial += fast_tanh(q_sh[u + 4] + k1.x) * wa_sh[u + 4];
        partial += fast_tanh(q_sh[u + 5] + k1.y) * wa_sh[u + 5];
        partial += fast_tanh(q_sh[u + 6] + k1.z) * wa_sh[u + 6];
        partial += fast_tanh(q_sh[u + 7] + k1.w) * wa_sh[u + 7];
    }
    partial += __shfl_xor(partial, 1);
    partial += __shfl_xor(partial, 2);
    if (j == 0) e_sh[sl] = (sl < W_) ? partial + ba[0] : -1e30f;
    __syncthreads();

    // softmax across 64 slots in wave 0 (out-of-band -> exp -> exactly 0)
    if (tid < 64) {
        float e = e_sh[tid];
        float m = e;
#pragma unroll
        for (int off = 1; off < 64; off <<= 1) m = fmaxf(m, __shfl_xor(m, off));
        float p = __expf(e - m);
        float sum = p;
#pragma unroll
        for (int off = 1; off < 64; off <<= 1) sum += __shfl_xor(sum, off);
        a_sh[tid] = p / sum;
    }
    __syncthreads();

    // step 4: lane = float4 feature chunk; wave w covers s = w*16 .. w*16+15
    int f4 = tid & 63;
    int w  = tid >> 6;
    const float4* xb4 = (const float4*)(x + (size_t)b * TT * FF);
    float4 acc = {0.f, 0.f, 0.f, 0.f};
#pragma unroll
    for (int i = 0; i < 16; ++i) {
        int s = w * 16 + i;
        int srow = min(s0 + s, TT - 1);      // clamp: invalid s has a==0
        float a = a_sh[s];
        float4 xv = xb4[(size_t)srow * (FF / 4) + f4];
        acc.x = fmaf(a, xv.x, acc.x);
        acc.y = fmaf(a, xv.y, acc.y);
        acc.z = fmaf(a, xv.z, acc.z);
        acc.w = fmaf(a, xv.w, acc.w);
    }
    red[w][f4] = acc;
    __syncthreads();
    if (tid < 64) {
        float4 r0 = red[0][tid], r1 = red[1][tid], r2 = red[2][tid], r3 = red[3][tid];
        float4 o = {r0.x + r1.x + r2.x + r3.x,
                    r0.y + r1.y + r2.y + r3.y,
                    r0.z + r1.z + r2.z + r3.z,
                    r0.w + r1.w + r2.w + r3.w};
        ((float4*)(out + (size_t)row * FF))[tid] = o;
    }
}

// ---------------------------------------------------------------------------
// Fallback (only if ws too small): fully fused, recomputes k per block.
// ---------------------------------------------------------------------------
__global__ __launch_bounds__(256) void fused_kernel(
    const float* __restrict__ x, const float* __restrict__ Wt,
    const float* __restrict__ Wx, const float* __restrict__ bh,
    const float* __restrict__ Wa, const float* __restrict__ ba,
    float* __restrict__ out) {
    int row = blockIdx.x;
    int t = row & (TT - 1);
    int b = row >> 10;
    int tid = threadIdx.x;
    int s0 = max(0, t - HALF_W);
    int s1 = min(TT, t + HALF_W);
    int W_ = s1 - s0;

    __shared__ float ks[WMAX * UU];   // 8 KB
    __shared__ float q_sh[UU];
    __shared__ float wa_sh[UU];
    __shared__ float e_sh[WMAX];
    __shared__ float a_sh[WMAX];

    if (tid < UU) {
        const float* xr = x + (size_t)row * FF;
        float acc = 0.f;
        for (int f = 0; f < FF; ++f) acc = fmaf(xr[f], Wt[f * UU + tid], acc);
        q_sh[tid]  = acc + bh[tid];
        wa_sh[tid] = Wa[tid];
    }
    for (int p = tid; p < W_ * UU; p += 256) {
        int sl = p >> 5, u = p & 31;
        const float* xr = x + (size_t)(b * TT + s0 + sl) * FF;
        float acc = 0.f;
        for (int f = 0; f < FF; ++f) acc = fmaf(xr[f], Wx[f * UU + u], acc);
        ks[p] = acc;
    }
    __syncthreads();

    int sl = tid >> 2;
    int j  = tid & 3;
    float partial = 0.f;
    if (sl < W_) {
#pragma unroll
        for (int uu = 0; uu < 8; ++uu) {
            int u = j * 8 + uu;
            partial += fast_tanh(q_sh[u] + ks[sl * UU + u]) * wa_sh[u];
        }
    }
    partial += __shfl_xor(partial, 1);
    partial += __shfl_xor(partial, 2);
    if (j == 0) e_sh[sl] = (sl < W_) ? partial + ba[0] : -1e30f;
    __syncthreads();

    if (tid < 64) {
        float e = e_sh[tid];
        float m = e;
#pragma unroll
        for (int off = 1; off < 64; off <<= 1) m = fmaxf(m, __shfl_xor(m, off));
        float p = __expf(e - m);
        float sum = p;
#pragma unroll
        for (int off = 1; off < 64; off <<= 1) sum += __shfl_xor(sum, off);
        a_sh[tid] = p / sum;
    }
    __syncthreads();

    float acc = 0.f;
    const float* xb = x + (size_t)(b * TT + s0) * FF + tid;
    for (int k2 = 0; k2 < W_; ++k2)
        acc = fmaf(a_sh[k2], xb[(size_t)k2 * FF], acc);
    out[(size_t)row * FF + tid] = acc;
}

extern "C" void kernel_launch(void* const* d_in, const int* in_sizes, int n_in,
                              void* d_out, int out_size, void* d_ws, size_t ws_size,
                              hipStream_t stream) {
    const float* x  = (const float*)d_in[0];
    const float* Wt = (const float*)d_in[1];
    const float* Wx = (const float*)d_in[2];
    const float* bh = (const float*)d_in[3];
    const float* Wa = (const float*)d_in[4];
    const float* ba = (const float*)d_in[5];
    float* out = (float*)d_out;

    const size_t need = (size_t)2 * BB * TT * UU * sizeof(float);   // 1 MiB
    if (ws_size >= need) {
        float* qbuf = (float*)d_ws;
        float* kbuf = qbuf + (size_t)BB * TT * UU;
        qk_kernel<<<BB * TT / RB, 256, 0, stream>>>(x, Wt, Wx, bh, qbuf, kbuf);
        attn_kernel<<<BB * TT, 256, 0, stream>>>(x, qbuf, kbuf, Wa, ba, out);
    } else {
        fused_kernel<<<BB * TT, 256, 0, stream>>>(x, Wt, Wx, bh, Wa, ba, out);
    }
}